// Round 16
// baseline (44.526 us; speedup 1.0000x reference)
//
#include <hip/hip_runtime.h>

// Weighted order statistic, B=4,C=3,K=3,NC=16,H=W=128, D=27, MD=54.
// One thread per (pixel, nc). Candidates are the 27 pairs +/-|m_d| where
// m_d = mask[nc,d] + patch[d]. Full 54-candidate descending order:
//   top    27: +|m| in descending |m| order
//   bottom 27: reverse complement of top (pair {v,-v} maps via ~key).
// ONE Batcher merge-exchange sort (n=27, 155 CEs) of exact |m|-keys
// (bits|0x80000000: exact monotone map of |m|) with packed payload
//   pack = (top_byteoff + nc*4) | ((bottom_byteoff + nc*4) << 16),
//   byteoff = weight_idx*64 into wT[54][16] (m>=0: top=d, bottom=d+27;
//   m<0: swapped) — literals + one cndmask + one add (nc-bias hoisted).
// Walk top positions 0..26 then bottom src 26..0 (key=~tk[src],
// off=pack[src]>>16) with ONE sequential f32 inclusive cumsum —
// bit-identical add order to the reference's jnp.cumsum. Walk LDS reads use
// base-folded addressing: ds_read vaddr = pack&0xFFFF, imm = wT's LDS base.
// Select last position with acc <= bias; fallback = tk[0] (max, li->0).
// Value = exact inverse of the key map.
// Staging destination-consecutive (R13: transposed LDS writes caused the
// bank conflicts, not the walk gather).
// __launch_bounds__(256,6): R16 occupancy-ladder probe — 85-reg budget,
// target 6 waves/SIMD (peak live ~79 regs; R15@(256,5) gave 48% occ, 43 µs).
// Output layout: reference reshapes (b*hw, NC) -> (b,NC,h,w) without
// transpose, so flat order is (b, hw, nc) -> out[n*NCH + nc].

#define NCH 16
#define DD  27
#define MDD 54
#define HH  128
#define WW  128
#define CCH 3

__global__ __launch_bounds__(256, 6) void wos_kernel(
    const float* __restrict__ xin,
    const float* __restrict__ mask,
    const float* __restrict__ weight,
    const float* __restrict__ bias,
    float* __restrict__ out)
{
  __shared__ float mT[DD * NCH];     // mask transposed [d][nc]
  __shared__ float wT[MDD * NCH];    // weights transposed [idx][nc]
  __shared__ float pL[16][DD + 1];   // patches (reads broadcast per pix group)
  __shared__ float bL[NCH];

  const int tid = threadIdx.x;
  // destination-consecutive staging: LDS writes conflict-free;
  // scattered global reads are L1/L2 hits (tiny tables).
  for (int j = tid; j < DD * NCH; j += 256)
    mT[j] = mask[(j & 15) * DD + (j >> 4)];
  for (int j = tid; j < MDD * NCH; j += 256)
    wT[j] = weight[(j & 15) * MDD + (j >> 4)];
  if (tid < NCH) bL[tid] = bias[tid];

  const int nc   = tid & 15;
  const int pix  = tid >> 4;
  const int base = (int)blockIdx.x * 16;

  // cooperative patch staging: 16 pixels x 27 taps, 'same' zero padding
  for (int i = tid; i < 16 * DD; i += 256) {
    const int pp = i / DD;
    const int d  = i - pp * DD;
    const int nn = base + pp;
    const int bb = nn >> 14;
    const int rr = nn & 16383;
    const int yy = rr >> 7;
    const int xx = rr & 127;
    const int c  = d / 9;
    const int ij = d - c * 9;
    const int di = ij / 3;
    const int dj = ij - di * 3;
    const int ys = yy + di - 1;
    const int xs = xx + dj - 1;
    const bool ok = ((unsigned)ys < (unsigned)HH) && ((unsigned)xs < (unsigned)WW);
    pL[pp][d] = ok ? xin[((bb * CCH + c) * HH + ys) * WW + xs] : 0.0f;
  }
  __syncthreads();

  const float t = bL[nc];
  const char* wbase = reinterpret_cast<const char*>(&wT[0]);

  // ---- build 27 exact |m|-keys + packed dual byte-offsets (nc-biased) ----
  const unsigned nc4p = (unsigned)(nc * 4) * 0x10001u;
  unsigned tk[DD], pack[DD];
  #pragma unroll
  for (int d = 0; d < DD; ++d) {
    const float m = mT[d * NCH + nc] + pL[pix][d];
    const unsigned bits = __float_as_uint(m);
    tk[d] = bits | 0x80000000u;                 // exact monotone key of |m|
    const unsigned pos_pack = (unsigned)(d * 64) | ((unsigned)((d + DD) * 64) << 16);
    const unsigned neg_pack = (unsigned)((d + DD) * 64) | ((unsigned)(d * 64) << 16);
    pack[d] = (((int)bits < 0) ? neg_pack : pos_pack) + nc4p;
  }

  // ---- Batcher merge-exchange sort, n=27, descending (155 CEs) ----
  {
    constexpr int P_[15][3] = {
      {16,16,0},{8,8,0},{8,8,8},{4,4,0},{4,12,4},{4,4,4},
      {2,2,0},{2,14,2},{2,6,2},{2,2,2},
      {1,1,0},{1,15,1},{1,7,1},{1,3,1},{1,1,1}};
    #pragma unroll
    for (int s = 0; s < 15; ++s) {
      const int p = P_[s][0], d = P_[s][1], r = P_[s][2];
      #pragma unroll
      for (int i = 0; i < DD; ++i) {
        if (((i & p) == r) && (i + d < DD)) {
          const int l = i + d;
          const unsigned ka = tk[i], kb = tk[l];
          const unsigned pa = pack[i], pb = pack[l];
          const bool sw = (ka < kb);
          tk[i] = sw ? kb : ka;     tk[l] = sw ? ka : kb;
          pack[i] = sw ? pb : pa;   pack[l] = sw ? pa : pb;
        }
      }
    }
  }

  // ---- walk: top positions 0..26 (+|m| desc), then bottom (= ~tk[26-pos]) ----
  float acc = 0.0f;
  unsigned ykey = tk[0];               // max real candidate (li clipped to 0)
  #pragma unroll
  for (int pos = 0; pos < DD; ++pos) {
    const float w = *reinterpret_cast<const float*>(wbase + (pack[pos] & 0xFFFFu));
    acc += w;
    ykey = (acc <= t) ? tk[pos] : ykey;
  }
  #pragma unroll
  for (int pos = 0; pos < DD; ++pos) {
    const int src = DD - 1 - pos;      // static index
    const float w = *reinterpret_cast<const float*>(wbase + (pack[src] >> 16));
    acc += w;
    const unsigned bkey = ~tk[src];
    ykey = (acc <= t) ? bkey : ykey;
  }

  // exact inverse of the key map
  const unsigned bits = (ykey & 0x80000000u) ? (ykey ^ 0x80000000u) : ~ykey;
  out[(base + pix) * NCH + nc] = __uint_as_float(bits);
}

extern "C" void kernel_launch(void* const* d_in, const int* in_sizes, int n_in,
                              void* d_out, int out_size, void* d_ws, size_t ws_size,
                              hipStream_t stream) {
  const float* x      = (const float*)d_in[0];
  const float* mask   = (const float*)d_in[1];
  const float* weight = (const float*)d_in[2];
  const float* bias   = (const float*)d_in[3];
  float* outp = (float*)d_out;

  dim3 grid(4096);   // 65536 pixels / 16 per block
  dim3 block(256);   // 16 pixels x 16 channels
  hipLaunchKernelGGL(wos_kernel, grid, block, 0, stream, x, mask, weight, bias, outp);
}

// Round 17
// 44.459 us; speedup vs baseline: 1.0015x; 1.0015x over previous
//
#include <hip/hip_runtime.h>

// Weighted order statistic, B=4,C=3,K=3,NC=16,H=W=128, D=27, MD=54.
// One thread per (pixel, nc). Candidates are the 27 pairs +/-|m_d| where
// m_d = mask[nc,d] + patch[d]. Full 54-candidate descending order:
//   top    27: +|m| in descending |m| order
//   bottom 27: reverse complement of top (pair {v,-v} maps via ~key).
// ONE Batcher merge-exchange sort (n=27, 155 CEs) of exact |m|-keys
// (bits|0x80000000: exact monotone map of |m|) with packed payload
//   pack = (top_byteoff + nc*4) | ((bottom_byteoff + nc*4) << 16),
//   byteoff = weight_idx*64 into wT[54][16] (m>=0: top=d, bottom=d+27;
//   m<0: swapped) — literals + one cndmask + one add (nc-bias hoisted).
// Walk top positions 0..26 then bottom src 26..0 (key=~tk[src],
// off=pack[src]>>16) with ONE sequential f32 inclusive cumsum —
// bit-identical add order to the reference's jnp.cumsum. Walk LDS reads use
// base-folded addressing: ds_read vaddr = pack&0xFFFF, imm = wT's LDS base.
// Select last position with acc <= bias; fallback = tk[0] (max, li->0).
// Value = exact inverse of the key map.
// Staging destination-consecutive (R13: transposed LDS writes caused the
// bank conflicts, not the walk gather).
// __launch_bounds__(256,5): R15's best (43.0 us, 48% occ). R16 showed
// (256,6) squeezes the allocator without raising occupancy — reverted.
// This round isolates the nc-biased pack (R16 bundled it with the bounds).
// Output layout: reference reshapes (b*hw, NC) -> (b,NC,h,w) without
// transpose, so flat order is (b, hw, nc) -> out[n*NCH + nc].

#define NCH 16
#define DD  27
#define MDD 54
#define HH  128
#define WW  128
#define CCH 3

__global__ __launch_bounds__(256, 5) void wos_kernel(
    const float* __restrict__ xin,
    const float* __restrict__ mask,
    const float* __restrict__ weight,
    const float* __restrict__ bias,
    float* __restrict__ out)
{
  __shared__ float mT[DD * NCH];     // mask transposed [d][nc]
  __shared__ float wT[MDD * NCH];    // weights transposed [idx][nc]
  __shared__ float pL[16][DD + 1];   // patches (reads broadcast per pix group)
  __shared__ float bL[NCH];

  const int tid = threadIdx.x;
  // destination-consecutive staging: LDS writes conflict-free;
  // scattered global reads are L1/L2 hits (tiny tables).
  for (int j = tid; j < DD * NCH; j += 256)
    mT[j] = mask[(j & 15) * DD + (j >> 4)];
  for (int j = tid; j < MDD * NCH; j += 256)
    wT[j] = weight[(j & 15) * MDD + (j >> 4)];
  if (tid < NCH) bL[tid] = bias[tid];

  const int nc   = tid & 15;
  const int pix  = tid >> 4;
  const int base = (int)blockIdx.x * 16;

  // cooperative patch staging: 16 pixels x 27 taps, 'same' zero padding
  for (int i = tid; i < 16 * DD; i += 256) {
    const int pp = i / DD;
    const int d  = i - pp * DD;
    const int nn = base + pp;
    const int bb = nn >> 14;
    const int rr = nn & 16383;
    const int yy = rr >> 7;
    const int xx = rr & 127;
    const int c  = d / 9;
    const int ij = d - c * 9;
    const int di = ij / 3;
    const int dj = ij - di * 3;
    const int ys = yy + di - 1;
    const int xs = xx + dj - 1;
    const bool ok = ((unsigned)ys < (unsigned)HH) && ((unsigned)xs < (unsigned)WW);
    pL[pp][d] = ok ? xin[((bb * CCH + c) * HH + ys) * WW + xs] : 0.0f;
  }
  __syncthreads();

  const float t = bL[nc];
  const char* wbase = reinterpret_cast<const char*>(&wT[0]);

  // ---- build 27 exact |m|-keys + packed dual byte-offsets (nc-biased) ----
  const unsigned nc4p = (unsigned)(nc * 4) * 0x10001u;
  unsigned tk[DD], pack[DD];
  #pragma unroll
  for (int d = 0; d < DD; ++d) {
    const float m = mT[d * NCH + nc] + pL[pix][d];
    const unsigned bits = __float_as_uint(m);
    tk[d] = bits | 0x80000000u;                 // exact monotone key of |m|
    const unsigned pos_pack = (unsigned)(d * 64) | ((unsigned)((d + DD) * 64) << 16);
    const unsigned neg_pack = (unsigned)((d + DD) * 64) | ((unsigned)(d * 64) << 16);
    pack[d] = (((int)bits < 0) ? neg_pack : pos_pack) + nc4p;
  }

  // ---- Batcher merge-exchange sort, n=27, descending (155 CEs) ----
  {
    constexpr int P_[15][3] = {
      {16,16,0},{8,8,0},{8,8,8},{4,4,0},{4,12,4},{4,4,4},
      {2,2,0},{2,14,2},{2,6,2},{2,2,2},
      {1,1,0},{1,15,1},{1,7,1},{1,3,1},{1,1,1}};
    #pragma unroll
    for (int s = 0; s < 15; ++s) {
      const int p = P_[s][0], d = P_[s][1], r = P_[s][2];
      #pragma unroll
      for (int i = 0; i < DD; ++i) {
        if (((i & p) == r) && (i + d < DD)) {
          const int l = i + d;
          const unsigned ka = tk[i], kb = tk[l];
          const unsigned pa = pack[i], pb = pack[l];
          const bool sw = (ka < kb);
          tk[i] = sw ? kb : ka;     tk[l] = sw ? ka : kb;
          pack[i] = sw ? pb : pa;   pack[l] = sw ? pa : pb;
        }
      }
    }
  }

  // ---- walk: top positions 0..26 (+|m| desc), then bottom (= ~tk[26-pos]) ----
  float acc = 0.0f;
  unsigned ykey = tk[0];               // max real candidate (li clipped to 0)
  #pragma unroll
  for (int pos = 0; pos < DD; ++pos) {
    const float w = *reinterpret_cast<const float*>(wbase + (pack[pos] & 0xFFFFu));
    acc += w;
    ykey = (acc <= t) ? tk[pos] : ykey;
  }
  #pragma unroll
  for (int pos = 0; pos < DD; ++pos) {
    const int src = DD - 1 - pos;      // static index
    const float w = *reinterpret_cast<const float*>(wbase + (pack[src] >> 16));
    acc += w;
    const unsigned bkey = ~tk[src];
    ykey = (acc <= t) ? bkey : ykey;
  }

  // exact inverse of the key map
  const unsigned bits = (ykey & 0x80000000u) ? (ykey ^ 0x80000000u) : ~ykey;
  out[(base + pix) * NCH + nc] = __uint_as_float(bits);
}

extern "C" void kernel_launch(void* const* d_in, const int* in_sizes, int n_in,
                              void* d_out, int out_size, void* d_ws, size_t ws_size,
                              hipStream_t stream) {
  const float* x      = (const float*)d_in[0];
  const float* mask   = (const float*)d_in[1];
  const float* weight = (const float*)d_in[2];
  const float* bias   = (const float*)d_in[3];
  float* outp = (float*)d_out;

  dim3 grid(4096);   // 65536 pixels / 16 per block
  dim3 block(256);   // 16 pixels x 16 channels
  hipLaunchKernelGGL(wos_kernel, grid, block, 0, stream, x, mask, weight, bias, outp);
}

// Round 18
// 42.789 us; speedup vs baseline: 1.0406x; 1.0390x over previous
//
#include <hip/hip_runtime.h>

// Weighted order statistic, B=4,C=3,K=3,NC=16,H=W=128, D=27, MD=54.
// One thread per (pixel, nc). Candidates are the 27 pairs +/-|m_d| where
// m_d = mask[nc,d] + patch[d]. Full 54-candidate descending order:
//   top    27: +|m| in descending |m| order
//   bottom 27: reverse complement of top (pair {v,-v} maps via ~key).
// ONE Batcher merge-exchange sort (n=27, 155 CEs) of exact |m|-keys
// (bits|0x80000000: exact monotone map of |m|) with packed payload
//   pack = top_byteoff | (bottom_byteoff << 16), byteoff = weight_idx*64
//   into wT[54][16] (m>=0: top=d, bottom=d+27; m<0: swapped) —
//   both variants compile-time literals, selected by one cndmask.
// Walk top positions 0..26 then bottom src 26..0 (key=~tk[src],
// off=pack[src]>>16) with ONE sequential f32 inclusive cumsum —
// bit-identical add order to the reference's jnp.cumsum. Select last
// position with acc <= bias; fallback = tk[0] (max, li clipped to 0).
// Value = exact inverse of the key map.
// Staging destination-consecutive (R13: transposed LDS writes caused the
// bank conflicts, not the walk gather). __launch_bounds__(256,5) = best
// occupancy point (R15: 48% occ). nc-biased pack REVERTED (R17: +1.5 us,
// SGPR 48->80). This is byte-identical to the R15 kernel (43.0 us best).
// Output layout: reference reshapes (b*hw, NC) -> (b,NC,h,w) without
// transpose, so flat order is (b, hw, nc) -> out[n*NCH + nc].

#define NCH 16
#define DD  27
#define MDD 54
#define HH  128
#define WW  128
#define CCH 3

__global__ __launch_bounds__(256, 5) void wos_kernel(
    const float* __restrict__ xin,
    const float* __restrict__ mask,
    const float* __restrict__ weight,
    const float* __restrict__ bias,
    float* __restrict__ out)
{
  __shared__ float mT[DD * NCH];     // mask transposed [d][nc]
  __shared__ float wT[MDD * NCH];    // weights transposed [idx][nc]
  __shared__ float pL[16][DD + 1];   // patches (reads broadcast per pix group)
  __shared__ float bL[NCH];

  const int tid = threadIdx.x;
  // destination-consecutive staging: LDS writes conflict-free;
  // scattered global reads are L1/L2 hits (tiny tables).
  for (int j = tid; j < DD * NCH; j += 256)
    mT[j] = mask[(j & 15) * DD + (j >> 4)];
  for (int j = tid; j < MDD * NCH; j += 256)
    wT[j] = weight[(j & 15) * MDD + (j >> 4)];
  if (tid < NCH) bL[tid] = bias[tid];

  const int nc   = tid & 15;
  const int pix  = tid >> 4;
  const int base = (int)blockIdx.x * 16;

  // cooperative patch staging: 16 pixels x 27 taps, 'same' zero padding
  for (int i = tid; i < 16 * DD; i += 256) {
    const int pp = i / DD;
    const int d  = i - pp * DD;
    const int nn = base + pp;
    const int bb = nn >> 14;
    const int rr = nn & 16383;
    const int yy = rr >> 7;
    const int xx = rr & 127;
    const int c  = d / 9;
    const int ij = d - c * 9;
    const int di = ij / 3;
    const int dj = ij - di * 3;
    const int ys = yy + di - 1;
    const int xs = xx + dj - 1;
    const bool ok = ((unsigned)ys < (unsigned)HH) && ((unsigned)xs < (unsigned)WW);
    pL[pp][d] = ok ? xin[((bb * CCH + c) * HH + ys) * WW + xs] : 0.0f;
  }
  __syncthreads();

  const float t = bL[nc];
  const char* wb = reinterpret_cast<const char*>(&wT[0]) + nc * 4;

  // ---- build 27 exact |m|-keys + packed dual byte-offsets ----
  unsigned tk[DD], pack[DD];
  #pragma unroll
  for (int d = 0; d < DD; ++d) {
    const float m = mT[d * NCH + nc] + pL[pix][d];
    const unsigned bits = __float_as_uint(m);
    tk[d] = bits | 0x80000000u;                 // exact monotone key of |m|
    const unsigned pos_pack = (unsigned)(d * 64) | ((unsigned)((d + DD) * 64) << 16);
    const unsigned neg_pack = (unsigned)((d + DD) * 64) | ((unsigned)(d * 64) << 16);
    pack[d] = ((int)bits < 0) ? neg_pack : pos_pack;   // both are literals
  }

  // ---- Batcher merge-exchange sort, n=27, descending (155 CEs) ----
  {
    constexpr int P_[15][3] = {
      {16,16,0},{8,8,0},{8,8,8},{4,4,0},{4,12,4},{4,4,4},
      {2,2,0},{2,14,2},{2,6,2},{2,2,2},
      {1,1,0},{1,15,1},{1,7,1},{1,3,1},{1,1,1}};
    #pragma unroll
    for (int s = 0; s < 15; ++s) {
      const int p = P_[s][0], d = P_[s][1], r = P_[s][2];
      #pragma unroll
      for (int i = 0; i < DD; ++i) {
        if (((i & p) == r) && (i + d < DD)) {
          const int l = i + d;
          const unsigned ka = tk[i], kb = tk[l];
          const unsigned pa = pack[i], pb = pack[l];
          const bool sw = (ka < kb);
          tk[i] = sw ? kb : ka;     tk[l] = sw ? ka : kb;
          pack[i] = sw ? pb : pa;   pack[l] = sw ? pa : pb;
        }
      }
    }
  }

  // ---- walk: top positions 0..26 (+|m| desc), then bottom (= ~tk[26-pos]) ----
  float acc = 0.0f;
  unsigned ykey = tk[0];               // max real candidate (li clipped to 0)
  #pragma unroll
  for (int pos = 0; pos < DD; ++pos) {
    const float w = *reinterpret_cast<const float*>(wb + (pack[pos] & 0xFFFFu));
    acc += w;
    ykey = (acc <= t) ? tk[pos] : ykey;
  }
  #pragma unroll
  for (int pos = 0; pos < DD; ++pos) {
    const int src = DD - 1 - pos;      // static index
    const float w = *reinterpret_cast<const float*>(wb + (pack[src] >> 16));
    acc += w;
    const unsigned bkey = ~tk[src];
    ykey = (acc <= t) ? bkey : ykey;
  }

  // exact inverse of the key map
  const unsigned bits = (ykey & 0x80000000u) ? (ykey ^ 0x80000000u) : ~ykey;
  out[(base + pix) * NCH + nc] = __uint_as_float(bits);
}

extern "C" void kernel_launch(void* const* d_in, const int* in_sizes, int n_in,
                              void* d_out, int out_size, void* d_ws, size_t ws_size,
                              hipStream_t stream) {
  const float* x      = (const float*)d_in[0];
  const float* mask   = (const float*)d_in[1];
  const float* weight = (const float*)d_in[2];
  const float* bias   = (const float*)d_in[3];
  float* outp = (float*)d_out;

  dim3 grid(4096);   // 65536 pixels / 16 per block
  dim3 block(256);   // 16 pixels x 16 channels
  hipLaunchKernelGGL(wos_kernel, grid, block, 0, stream, x, mask, weight, bias, outp);
}